// Round 1
// baseline (337.051 us; speedup 1.0000x reference)
//
#include <hip/hip_runtime.h>
#include <hip/hip_bf16.h>

// QuantLinearAWQ: out[T,N] = x[T,K] @ ((q - z) * s)[K,N] + bias[N]
// T=32, K=4096, N=11008, group=128. qweight int32 codes (180 MB) dominate
// traffic -> memory-bound (~29us floor @6.3TB/s). Each weight read ONCE,
// reused across all 32 tokens in-register.

#define TOKENS   32
#define KDIM     4096
#define NDIM     11008
#define GS       128
#define KSPLIT   16
#define KCHUNK   (KDIM / KSPLIT)   // 256 = 2 quant groups
#define XS_STRIDE 36               // 144 B rows: 16B-aligned for ds_read_b128

__global__ __launch_bounds__(256) void awq_init_kernel(
    const float* __restrict__ bias, float* __restrict__ out)
{
    // grid (43, 32): 43*256 == 11008 exactly
    const int n = blockIdx.x * 256 + threadIdx.x;
    out[blockIdx.y * NDIM + n] = bias[n];
}

__global__ __launch_bounds__(256) void awq_gemm_kernel(
    const float* __restrict__ x,
    const int*   __restrict__ qw,
    const int*   __restrict__ qz,
    const float* __restrict__ sc,
    float*       __restrict__ out)
{
    __shared__ float xs[KCHUNK * XS_STRIDE];

    const int tid = threadIdx.x;
    const int kc0 = blockIdx.y * KCHUNK;

    // Stage x[0:32][kc0:kc0+256] transposed into LDS: xs[k_local][t].
    // Global reads coalesced (row-contiguous); LDS write conflicts (8-way at
    // stride 36) happen once per 256 k-iterations -> ~1.5% of block time.
    #pragma unroll
    for (int t = 0; t < TOKENS; ++t) {
        xs[tid * XS_STRIDE + t] = x[t * KDIM + kc0 + tid];
    }
    __syncthreads();

    const int n0 = blockIdx.x * 512 + tid * 2;
    if (n0 >= NDIM) return;   // tail block (bx=21) only half active

    float accA[TOKENS];
    float accB[TOKENS];
    #pragma unroll
    for (int t = 0; t < TOKENS; ++t) { accA[t] = 0.f; accB[t] = 0.f; }

    #pragma unroll
    for (int g = 0; g < KCHUNK / GS; ++g) {
        const int grp = kc0 / GS + g;
        // (q-8) - (z-8) == q - z : recentering cancels.
        // w = (q - z)*s = fma(q, s, -z*s)
        const float s0 = sc[grp * NDIM + n0];
        const float s1 = sc[grp * NDIM + n0 + 1];
        const int2  zz = *(const int2*)&qz[grp * NDIM + n0];
        const float nzs0 = -(float)zz.x * s0;
        const float nzs1 = -(float)zz.y * s1;

        const int* qp = qw + (size_t)(kc0 + g * GS) * NDIM + n0;

        #pragma unroll 8
        for (int kk = 0; kk < GS; ++kk) {
            const int2 q = *(const int2*)qp;   // 8B/lane coalesced dwordx2
            qp += NDIM;
            const float w0 = fmaf((float)q.x, s0, nzs0);
            const float w1 = fmaf((float)q.y, s1, nzs1);

            const float4* xp = (const float4*)&xs[(g * GS + kk) * XS_STRIDE];
            #pragma unroll
            for (int t4 = 0; t4 < 8; ++t4) {
                const float4 xv = xp[t4];   // broadcast ds_read_b128
                accA[t4*4+0] = fmaf(w0, xv.x, accA[t4*4+0]);
                accB[t4*4+0] = fmaf(w1, xv.x, accB[t4*4+0]);
                accA[t4*4+1] = fmaf(w0, xv.y, accA[t4*4+1]);
                accB[t4*4+1] = fmaf(w1, xv.y, accB[t4*4+1]);
                accA[t4*4+2] = fmaf(w0, xv.z, accA[t4*4+2]);
                accB[t4*4+2] = fmaf(w1, xv.z, accB[t4*4+2]);
                accA[t4*4+3] = fmaf(w0, xv.w, accA[t4*4+3]);
                accB[t4*4+3] = fmaf(w1, xv.w, accB[t4*4+3]);
            }
        }
    }

    // Combine K-split partials: HW fp32 atomics (global_atomic_add_f32),
    // distinct addresses, ~11 MB L2 traffic total.
    float* op = out + n0;
    #pragma unroll
    for (int t = 0; t < TOKENS; ++t) {
        unsafeAtomicAdd(op + (size_t)t * NDIM,     accA[t]);
        unsafeAtomicAdd(op + (size_t)t * NDIM + 1, accB[t]);
    }
}

extern "C" void kernel_launch(void* const* d_in, const int* in_sizes, int n_in,
                              void* d_out, int out_size, void* d_ws, size_t ws_size,
                              hipStream_t stream) {
    const float* x    = (const float*)d_in[0];
    const int*   qw   = (const int*)  d_in[1];
    const int*   qz   = (const int*)  d_in[2];
    const float* sc   = (const float*)d_in[3];
    const float* bias = (const float*)d_in[4];
    float* out = (float*)d_out;

    // 1) out = broadcast(bias)   (d_out is poisoned 0xAA before every launch)
    awq_init_kernel<<<dim3(NDIM / 256, TOKENS), 256, 0, stream>>>(bias, out);
    // 2) out += x @ W_deq, K split 16 ways, atomically combined
    awq_gemm_kernel<<<dim3((NDIM + 511) / 512, KSPLIT), 256, 0, stream>>>(
        x, qw, qz, sc, out);
}